// Round 13
// baseline (2037.009 us; speedup 1.0000x reference)
//
#include <hip/hip_runtime.h>
#include <math.h>

#define H 51
#define LSEQ 999
#define BTOT 2048
#define E 4
#define NBLK (BTOT / E)     // 512 blocks -> 2 co-resident blocks/CU (independent barriers)

#define ROWS 256            // 64 units * 4 gates (unit-major rows: row = u*4+m)
#define K1 64               // layer1 K: k=0..50 h1, k=62 const-1 (bias), k=63 x
#define K2 128              // layer2 K: k=0..50 h1, k=62 const-1 (bias), k=64..114 h2

// ws float offsets
#define WS_W1 0
#define WS_W2 (WS_W1 + ROWS * K1)
#define WS_WL (WS_W2 + ROWS * K2)
#define WS_BL (WS_WL + 64)

// LDS frames: 1 frame = one 32-K B-fragment plane (64 lanes x 16B); h is bf16 hi-only
#define FRAME 1024
#define NFRAMES 8
#define PART_OFF (NFRAMES * FRAME)
#define LDS_BYTES (PART_OFF + 2 * 128 * 4)   // double-buffered partials (8 waves x 16)

#define F_L1(b, s) ((b) * 2 + (s))        // [h1; 1; x] B-frags, double-buffered: 0..3
#define F_H2(b, s) (4 + (b) * 2 + (s))    // h2 B-frags, double-buffered: 4..7

typedef __attribute__((ext_vector_type(8))) short bf16x8;
typedef __attribute__((ext_vector_type(4))) float f32x4;

// ---------------- prep: padded cat-matrices, unit-major rows ----------------
// W1''[R][k]: k<51 = Whh1, k=62 = b1 (bias via const-1 slot), k=63 = Wih1
// W2''[R][k]: k<51 = Wih2 (h1 input), k=62 = b2, k=64..114 = Whh2
__global__ void prep_kernel(const float* __restrict__ Wih1, const float* __restrict__ Whh1,
                            const float* __restrict__ bih1, const float* __restrict__ bhh1,
                            const float* __restrict__ Wih2, const float* __restrict__ Whh2,
                            const float* __restrict__ bih2, const float* __restrict__ bhh2,
                            const float* __restrict__ Wlin, const float* __restrict__ blin,
                            float* __restrict__ ws) {
    int tid = threadIdx.x + blockIdx.x * blockDim.x;
    int nthr = blockDim.x * gridDim.x;
    for (int idx = tid; idx < ROWS * K1; idx += nthr) {
        int R = idx / K1, k = idx % K1;
        int u = R >> 2, m = R & 3;
        float v = 0.0f;
        if (u < H) {
            if (k < H) v = Whh1[(m * H + u) * H + k];
            else if (k == 62) v = bih1[m * H + u] + bhh1[m * H + u];
            else if (k == 63) v = Wih1[m * H + u];   // Wih1 is [204][1]
        }
        ws[WS_W1 + idx] = v;
    }
    for (int idx = tid; idx < ROWS * K2; idx += nthr) {
        int R = idx / K2, k = idx % K2;
        int u = R >> 2, m = R & 3;
        float v = 0.0f;
        if (u < H) {
            if (k < H) v = Wih2[(m * H + u) * H + k];
            else if (k == 62) v = bih2[m * H + u] + bhh2[m * H + u];
            else if (k >= 64 && k < 64 + H) v = Whh2[(m * H + u) * H + (k - 64)];
        }
        ws[WS_W2 + idx] = v;
    }
    for (int u = tid; u < 64; u += nthr) ws[WS_WL + u] = (u < H) ? Wlin[u] : 0.0f;
    if (tid == 0) ws[WS_BL] = blin[0];
}

// ---------------- helpers ----------------
__device__ __forceinline__ short f2bf(float f) {      // round-to-nearest-even
    unsigned u = __float_as_uint(f);
    unsigned r = (u + 0x7fffu + ((u >> 16) & 1u)) >> 16;
    return (short)r;
}
__device__ __forceinline__ float bf2f(short b) {
    return __uint_as_float(((unsigned)(unsigned short)b) << 16);
}
__device__ __forceinline__ float sigm(float x) {
    return __builtin_amdgcn_rcpf(1.0f + __expf(-x));
}
__device__ __forceinline__ float tanh_(float x) {
    return fmaf(-2.0f, __builtin_amdgcn_rcpf(__expf(2.0f * x) + 1.0f), 1.0f);
}
// scatter one bf16 h value into B-fragment layout: elems 0..3 <-> k=4g+j, 4..7 <-> 16+4g+j
__device__ __forceinline__ void wr1(char* base, int f, int k, int e, short hi) {
    const int kk = k & 31;
    const int gg = (kk & 15) >> 2;
    const int j  = (kk & 3) + ((kk >> 4) << 2);
    const int off = (gg * 16 + e) * 16 + j * 2;
    *(short*)(base + (size_t)f * FRAME + off) = hi;
}
__device__ __forceinline__ bf16x8 ld_fr(const char* base, int f, int l) {
    return *(const bf16x8*)(base + (size_t)f * FRAME + (size_t)l * 16);
}

// --- main kernel: 8 waves x 2 row-tiles, E=4, h hi-only, 2 blocks/CU anti-phase ---
__global__ void __launch_bounds__(512, 2)
lstm_kernel(const float* __restrict__ x, const float* __restrict__ ws,
            float* __restrict__ out) {
    __shared__ __align__(16) char smem[LDS_BYTES];

    const int tid = threadIdx.x;
    const int w = tid >> 6;        // 0..7; each wave owns 2 row-tiles T = w*2+i
    const int l = tid & 63;
    const int g = l >> 4;
    const int e = l & 15;

    for (int i = tid; i < LDS_BYTES / 4; i += 512) ((float*)smem)[i] = 0.0f;

    // ---- prologue: register-resident W fragments (hi/lo bf16 split; weights exact) ----
    bf16x8 w1h[2][2], w1l[2][2], w2h[2][4], w2l[2][4];
    float wlr[2];
#pragma unroll
    for (int i = 0; i < 2; ++i) {
        const int T = w * 2 + i;
        const int rowA = T * 16 + e;
#pragma unroll
        for (int s = 0; s < 2; ++s) {
            bf16x8 hh, ll;
#pragma unroll
            for (int j = 0; j < 8; ++j) {
                const int k = s * 32 + ((j < 4) ? (4 * g + j) : (16 + 4 * g + (j - 4)));
                float wv = ws[WS_W1 + rowA * K1 + k];
                short hb = f2bf(wv);
                hh[j] = hb;
                ll[j] = f2bf(wv - bf2f(hb));
            }
            w1h[i][s] = hh; w1l[i][s] = ll;
        }
#pragma unroll
        for (int s = 0; s < 4; ++s) {
            bf16x8 hh, ll;
#pragma unroll
            for (int j = 0; j < 8; ++j) {
                const int k = s * 32 + ((j < 4) ? (4 * g + j) : (16 + 4 * g + (j - 4)));
                float wv = ws[WS_W2 + rowA * K2 + k];
                short hb = f2bf(wv);
                hh[j] = hb;
                ll[j] = f2bf(wv - bf2f(hb));
            }
            w2h[i][s] = hh; w2l[i][s] = ll;
        }
        wlr[i] = ws[WS_WL + T * 4 + g];
    }
    const float blv = ws[WS_BL];

    const int b0 = blockIdx.x * E;
    const float* xp = x + (size_t)(b0 + (l & 3)) * LSEQ;   // valid for lanes l<4
    float* pparts = (float*)(smem + PART_OFF);

    __syncthreads();   // zero-init complete

    // const-1 (bf16 1.0) at k=62 of both a1 buffers (bias slot; u<62 guard protects it)
    if (tid < 32) {
        const int bb = tid >> 4, ee = tid & 15;
        // k=62 -> kk=30: gg=3, j=6 -> off=(48+ee)*16+12
        *(short*)(smem + (size_t)F_L1(bb, 1) * FRAME + (48 + ee) * 16 + 12) = (short)0x3F80;
    }
    float xv = 0.0f;
    if (w == 0 && l < 4) {
        float x0 = xp[0];
        wr1(smem, F_L1(0, 1), 63, l, f2bf(x0));   // x(0) -> buf0 k=63
        xv = xp[1];                                // x(1), written at phase 0
    }

    float c1s[2] = {0.f, 0.f};
    float c2s[2] = {0.f, 0.f};

    __syncthreads();   // x(0) + const-1 visible

    // Phase t: L1 computes h1(t) from a1 = [h1(t-1); 1; x(t)] (buf q=t&1);
    //          L2 computes h2(t-1), out-partials(t-1) from same a1 + h2(t-2) (F_H2 buf q).
    for (int t = 0; t <= LSEQ; ++t) {
        const int q = t & 1;

        // ---- phase-start loads: 4 b128 per lane ----
        bf16x8 a1f[2], h2f[2];
#pragma unroll
        for (int s = 0; s < 2; ++s) {
            a1f[s] = ld_fr(smem, F_L1(q, s), l);
            h2f[s] = ld_fr(smem, F_H2(q, s), l);
        }

        // out(t-2): gather partials written at phase t-1 (buffer q^1)
        if (w == 1 && l < 4 && t >= 2) {
            const float* pp = pparts + (q ^ 1) * 128;
            float r = ((pp[l] + pp[16 + l]) + (pp[32 + l] + pp[48 + l])) +
                      ((pp[64 + l] + pp[80 + l]) + (pp[96 + l] + pp[112 + l]));
            out[(size_t)(b0 + l) * LSEQ + (t - 2)] = r + blv;
        }

        // write x(t+1) into next a1 buf; prefetch x(t+2)
        float xnew = 0.0f;
        if (w == 0 && l < 4) {
            xnew = xp[(t + 2 < LSEQ) ? (t + 2) : (LSEQ - 1)];
            wr1(smem, F_L1(q ^ 1, 1), 63, l, f2bf(xv));
        }

        // ---- MFMAs: 24 per wave, 6 independent 4-deep chains ----
        f32x4 acc1[2], acc2a[2], acc2b[2];
#pragma unroll
        for (int i = 0; i < 2; ++i) {
            acc1[i]  = (f32x4){0.f, 0.f, 0.f, 0.f};
            acc2a[i] = (f32x4){0.f, 0.f, 0.f, 0.f};
            acc2b[i] = (f32x4){0.f, 0.f, 0.f, 0.f};
        }
        __builtin_amdgcn_s_setprio(1);
#pragma unroll
        for (int s = 0; s < 2; ++s)
#pragma unroll
            for (int i = 0; i < 2; ++i) {
                acc1[i]  = __builtin_amdgcn_mfma_f32_16x16x32_bf16(w1h[i][s],     a1f[s], acc1[i],  0, 0, 0);
                acc2a[i] = __builtin_amdgcn_mfma_f32_16x16x32_bf16(w2h[i][s],     a1f[s], acc2a[i], 0, 0, 0);
                acc2b[i] = __builtin_amdgcn_mfma_f32_16x16x32_bf16(w2h[i][s + 2], h2f[s], acc2b[i], 0, 0, 0);
                acc1[i]  = __builtin_amdgcn_mfma_f32_16x16x32_bf16(w1l[i][s],     a1f[s], acc1[i],  0, 0, 0);
                acc2a[i] = __builtin_amdgcn_mfma_f32_16x16x32_bf16(w2l[i][s],     a1f[s], acc2a[i], 0, 0, 0);
                acc2b[i] = __builtin_amdgcn_mfma_f32_16x16x32_bf16(w2l[i][s + 2], h2f[s], acc2b[i], 0, 0, 0);
            }
        __builtin_amdgcn_s_setprio(0);

        // ---- L1 activations -> h1(t) scatter into F_L1(q^1) (hi plane only) ----
#pragma unroll
        for (int i = 0; i < 2; ++i) {
            float ig = sigm(acc1[i][0]), fg = sigm(acc1[i][1]);
            float gg = tanh_(acc1[i][2]), og = sigm(acc1[i][3]);
            c1s[i] = fg * c1s[i] + ig * gg;
            float h1 = og * tanh_(c1s[i]);
            const int u = (w * 2 + i) * 4 + g;
            if (u < 62) wr1(smem, F_L1(q ^ 1, u >> 5), u, e, f2bf(h1));  // 62=const,63=x
        }

        // ---- L2 activations (step t-1) -> h2 scatter + output partial ----
        if (t > 0) {
            float pr = 0.0f;
#pragma unroll
            for (int i = 0; i < 2; ++i) {
                f32x4 a2 = acc2a[i] + acc2b[i];
                float ig = sigm(a2[0]), fg = sigm(a2[1]);
                float gg = tanh_(a2[2]), og = sigm(a2[3]);
                c2s[i] = fg * c2s[i] + ig * gg;
                float h2 = og * tanh_(c2s[i]);
                const int u = (w * 2 + i) * 4 + g;
                wr1(smem, F_H2(q ^ 1, u >> 5), u, e, f2bf(h2));
                pr = fmaf(wlr[i], h2, pr);
            }
            pr += __shfl_xor(pr, 16);
            pr += __shfl_xor(pr, 32);
            if (l < 16) pparts[q * 128 + w * 16 + l] = pr;
        }

        __syncthreads();
        xv = xnew;
    }

    // final output: out(LSEQ-1) from partials written at phase LSEQ
    if (w == 1 && l < 4) {
        const float* pp = pparts + (LSEQ & 1) * 128;
        float r = ((pp[l] + pp[16 + l]) + (pp[32 + l] + pp[48 + l])) +
                  ((pp[64 + l] + pp[80 + l]) + (pp[96 + l] + pp[112 + l]));
        out[(size_t)(b0 + l) * LSEQ + (LSEQ - 1)] = r + blv;
    }
}

extern "C" void kernel_launch(void* const* d_in, const int* in_sizes, int n_in,
                              void* d_out, int out_size, void* d_ws, size_t ws_size,
                              hipStream_t stream) {
    const float* x    = (const float*)d_in[0];
    const float* Wih1 = (const float*)d_in[1];
    const float* Whh1 = (const float*)d_in[2];
    const float* bih1 = (const float*)d_in[3];
    const float* bhh1 = (const float*)d_in[4];
    const float* Wih2 = (const float*)d_in[5];
    const float* Whh2 = (const float*)d_in[6];
    const float* bih2 = (const float*)d_in[7];
    const float* bhh2 = (const float*)d_in[8];
    const float* Wlin = (const float*)d_in[9];
    const float* blin = (const float*)d_in[10];
    float* ws  = (float*)d_ws;
    float* out = (float*)d_out;

    hipLaunchKernelGGL(prep_kernel, dim3(64), dim3(256), 0, stream,
                       Wih1, Whh1, bih1, bhh1, Wih2, Whh2, bih2, bhh2, Wlin, blin, ws);
    hipLaunchKernelGGL(lstm_kernel, dim3(NBLK), dim3(512), 0, stream, x, ws, out);
}

// Round 14
// 1157.816 us; speedup vs baseline: 1.7594x; 1.7594x over previous
//
#include <hip/hip_runtime.h>
#include <math.h>

#define H 51
#define LSEQ 999
#define BTOT 2048
#define E 16
#define NBLK (BTOT / E)     // 128 blocks

#define ROWS 256            // 64 units * 4 gates (unit-major rows: row = u*4+m)
#define K1 64               // layer1 K: k=0..50 h1, k=62 const-1 (bias), k=63 x
#define K2 128              // layer2 K: k=0..50 h1, k=62 const-1 (bias), k=64..114 h2

// ws float offsets
#define WS_W1 0
#define WS_W2 (WS_W1 + ROWS * K1)
#define WS_WL (WS_W2 + ROWS * K2)
#define WS_BL (WS_WL + 64)

// LDS frames: 1 frame = one 32-K B-fragment plane (64 lanes x 16B); h is bf16 hi-only
#define FRAME 1024
#define NFRAMES 8
#define PART_OFF (NFRAMES * FRAME)
#define LDS_BYTES (PART_OFF + 2 * 128 * 4)   // double-buffered partials (8 waves x 16)

#define F_L1(b, s) ((b) * 2 + (s))        // [h1; 1; x] B-frags, double-buffered: 0..3
#define F_H2(b, s) (4 + (b) * 2 + (s))    // h2 B-frags, double-buffered: 4..7

typedef __attribute__((ext_vector_type(8))) short bf16x8;
typedef __attribute__((ext_vector_type(4))) float f32x4;

// ---------------- prep: padded cat-matrices, unit-major rows ----------------
// W1''[R][k]: k<51 = Whh1, k=62 = b1 (bias via const-1 slot), k=63 = Wih1
// W2''[R][k]: k<51 = Wih2 (h1 input), k=62 = b2, k=64..114 = Whh2
__global__ void prep_kernel(const float* __restrict__ Wih1, const float* __restrict__ Whh1,
                            const float* __restrict__ bih1, const float* __restrict__ bhh1,
                            const float* __restrict__ Wih2, const float* __restrict__ Whh2,
                            const float* __restrict__ bih2, const float* __restrict__ bhh2,
                            const float* __restrict__ Wlin, const float* __restrict__ blin,
                            float* __restrict__ ws) {
    int tid = threadIdx.x + blockIdx.x * blockDim.x;
    int nthr = blockDim.x * gridDim.x;
    for (int idx = tid; idx < ROWS * K1; idx += nthr) {
        int R = idx / K1, k = idx % K1;
        int u = R >> 2, m = R & 3;
        float v = 0.0f;
        if (u < H) {
            if (k < H) v = Whh1[(m * H + u) * H + k];
            else if (k == 62) v = bih1[m * H + u] + bhh1[m * H + u];
            else if (k == 63) v = Wih1[m * H + u];   // Wih1 is [204][1]
        }
        ws[WS_W1 + idx] = v;
    }
    for (int idx = tid; idx < ROWS * K2; idx += nthr) {
        int R = idx / K2, k = idx % K2;
        int u = R >> 2, m = R & 3;
        float v = 0.0f;
        if (u < H) {
            if (k < H) v = Wih2[(m * H + u) * H + k];
            else if (k == 62) v = bih2[m * H + u] + bhh2[m * H + u];
            else if (k >= 64 && k < 64 + H) v = Whh2[(m * H + u) * H + (k - 64)];
        }
        ws[WS_W2 + idx] = v;
    }
    for (int u = tid; u < 64; u += nthr) ws[WS_WL + u] = (u < H) ? Wlin[u] : 0.0f;
    if (tid == 0) ws[WS_BL] = blin[0];
}

// ---------------- helpers ----------------
__device__ __forceinline__ short f2bf(float f) {      // round-to-nearest-even
    unsigned u = __float_as_uint(f);
    unsigned r = (u + 0x7fffu + ((u >> 16) & 1u)) >> 16;
    return (short)r;
}
__device__ __forceinline__ float bf2f(short b) {
    return __uint_as_float(((unsigned)(unsigned short)b) << 16);
}
__device__ __forceinline__ float sigm(float x) {
    return __builtin_amdgcn_rcpf(1.0f + __expf(-x));
}
__device__ __forceinline__ float tanh_(float x) {
    return fmaf(-2.0f, __builtin_amdgcn_rcpf(__expf(2.0f * x) + 1.0f), 1.0f);
}
// scatter one bf16 h value into B-fragment layout: elems 0..3 <-> k=4g+j, 4..7 <-> 16+4g+j
__device__ __forceinline__ void wr1(char* base, int f, int k, int e, short hi) {
    const int kk = k & 31;
    const int gg = (kk & 15) >> 2;
    const int j  = (kk & 3) + ((kk >> 4) << 2);
    const int off = (gg * 16 + e) * 16 + j * 2;
    *(short*)(base + (size_t)f * FRAME + off) = hi;
}
__device__ __forceinline__ bf16x8 ld_fr(const char* base, int f, int l) {
    return *(const bf16x8*)(base + (size_t)f * FRAME + (size_t)l * 16);
}

// ---- main kernel: 8 waves x 2 row-tiles, E=16, h hi-only, staggered A/B wave order ----
__global__ void __launch_bounds__(512, 1)
lstm_kernel(const float* __restrict__ x, const float* __restrict__ ws,
            float* __restrict__ out) {
    __shared__ __align__(16) char smem[LDS_BYTES];

    const int tid = threadIdx.x;
    const int w = tid >> 6;        // 0..7; each wave owns 2 row-tiles T = w*2+i
    const int l = tid & 63;
    const int g = l >> 4;
    const int e = l & 15;
    const int roleB = (w >> 2) & 1;   // SIMD s hosts wave s (A) and wave s+4 (B)

    for (int i = tid; i < LDS_BYTES / 4; i += 512) ((float*)smem)[i] = 0.0f;

    // ---- prologue: register-resident W fragments (hi/lo bf16 split; weights exact) ----
    bf16x8 w1h[2][2], w1l[2][2], w2h[2][4], w2l[2][4];
    float wlr[2];
#pragma unroll
    for (int i = 0; i < 2; ++i) {
        const int T = w * 2 + i;
        const int rowA = T * 16 + e;
#pragma unroll
        for (int s = 0; s < 2; ++s) {
            bf16x8 hh, ll;
#pragma unroll
            for (int j = 0; j < 8; ++j) {
                const int k = s * 32 + ((j < 4) ? (4 * g + j) : (16 + 4 * g + (j - 4)));
                float wv = ws[WS_W1 + rowA * K1 + k];
                short hb = f2bf(wv);
                hh[j] = hb;
                ll[j] = f2bf(wv - bf2f(hb));
            }
            w1h[i][s] = hh; w1l[i][s] = ll;
        }
#pragma unroll
        for (int s = 0; s < 4; ++s) {
            bf16x8 hh, ll;
#pragma unroll
            for (int j = 0; j < 8; ++j) {
                const int k = s * 32 + ((j < 4) ? (4 * g + j) : (16 + 4 * g + (j - 4)));
                float wv = ws[WS_W2 + rowA * K2 + k];
                short hb = f2bf(wv);
                hh[j] = hb;
                ll[j] = f2bf(wv - bf2f(hb));
            }
            w2h[i][s] = hh; w2l[i][s] = ll;
        }
        wlr[i] = ws[WS_WL + T * 4 + g];
    }
    const float blv = ws[WS_BL];

    const int b0 = blockIdx.x * E;
    const float* xp = x + (size_t)(b0 + e) * LSEQ;   // used by wave0 lanes<16 only
    float* pparts = (float*)(smem + PART_OFF);

    __syncthreads();   // zero-init complete

    // const-1 (bf16 1.0) at k=62 of both a1 buffers (bias slot; u<62 guard protects it)
    if (tid < 32) {
        const int bb = tid >> 4, ee = tid & 15;
        // k=62 -> kk=30: gg=3, j=6 -> off=(48+ee)*16+12
        *(short*)(smem + (size_t)F_L1(bb, 1) * FRAME + (48 + ee) * 16 + 12) = (short)0x3F80;
    }
    float xv = 0.0f;
    if (w == 0 && l < 16) {
        float x0 = xp[0];
        wr1(smem, F_L1(0, 1), 63, e, f2bf(x0));   // x(0) -> buf0 k=63
        xv = xp[1];                                // x(1), written at phase 0
    }

    float c1s[2] = {0.f, 0.f};
    float c2s[2] = {0.f, 0.f};

    __syncthreads();   // x(0) + const-1 visible

    // Phase t: L1 computes h1(t) from a1 = [h1(t-1); 1; x(t)] (buf q=t&1);
    //          L2 computes h2(t-1), out-partials(t-1) from same a1 + h2(t-2) (F_H2 buf q).
    // Waves 0-3 (A-order) and 4-7 (B-order) traverse the phase in opposite pipe order
    // so the two waves sharing each SIMD are never in the same burst stage (anti-lockstep).
    for (int t = 0; t <= LSEQ; ++t) {
        const int q = t & 1;

        bf16x8 a1f[2], h2f[2];
        f32x4 acc1[2], acc2a[2], acc2b[2];
#pragma unroll
        for (int i = 0; i < 2; ++i) {
            acc1[i]  = (f32x4){0.f, 0.f, 0.f, 0.f};
            acc2a[i] = (f32x4){0.f, 0.f, 0.f, 0.f};
            acc2b[i] = (f32x4){0.f, 0.f, 0.f, 0.f};
        }

        if (!roleB) {
            // ======== A-order: a1 -> acc1/acc2a -> h2 -> acc2b -> L1 acts -> L2 acts ====
#pragma unroll
            for (int s = 0; s < 2; ++s) a1f[s] = ld_fr(smem, F_L1(q, s), l);

            // out(t-2) gather (wave 1) and x(t+1) staging (wave 0) — role-A housekeeping
            if (w == 1 && l < 16 && t >= 2) {
                const float* pp = pparts + (q ^ 1) * 128;
                float r = ((pp[l] + pp[16 + l]) + (pp[32 + l] + pp[48 + l])) +
                          ((pp[64 + l] + pp[80 + l]) + (pp[96 + l] + pp[112 + l]));
                out[(size_t)(b0 + l) * LSEQ + (t - 2)] = r + blv;
            }
            float xnew = 0.0f;
            if (w == 0 && l < 16) {
                xnew = xp[(t + 2 < LSEQ) ? (t + 2) : (LSEQ - 1)];
                wr1(smem, F_L1(q ^ 1, 1), 63, e, f2bf(xv));
            }

            __builtin_amdgcn_s_setprio(1);
#pragma unroll
            for (int s = 0; s < 2; ++s)
#pragma unroll
                for (int i = 0; i < 2; ++i) {
                    acc1[i]  = __builtin_amdgcn_mfma_f32_16x16x32_bf16(w1h[i][s], a1f[s], acc1[i],  0, 0, 0);
                    acc2a[i] = __builtin_amdgcn_mfma_f32_16x16x32_bf16(w2h[i][s], a1f[s], acc2a[i], 0, 0, 0);
                    acc1[i]  = __builtin_amdgcn_mfma_f32_16x16x32_bf16(w1l[i][s], a1f[s], acc1[i],  0, 0, 0);
                    acc2a[i] = __builtin_amdgcn_mfma_f32_16x16x32_bf16(w2l[i][s], a1f[s], acc2a[i], 0, 0, 0);
                }
#pragma unroll
            for (int s = 0; s < 2; ++s) h2f[s] = ld_fr(smem, F_H2(q, s), l);
#pragma unroll
            for (int s = 0; s < 2; ++s)
#pragma unroll
                for (int i = 0; i < 2; ++i) {
                    acc2b[i] = __builtin_amdgcn_mfma_f32_16x16x32_bf16(w2h[i][s + 2], h2f[s], acc2b[i], 0, 0, 0);
                    acc2b[i] = __builtin_amdgcn_mfma_f32_16x16x32_bf16(w2l[i][s + 2], h2f[s], acc2b[i], 0, 0, 0);
                }
            __builtin_amdgcn_s_setprio(0);

            // L1 acts -> h1(t)
#pragma unroll
            for (int i = 0; i < 2; ++i) {
                float ig = sigm(acc1[i][0]), fg = sigm(acc1[i][1]);
                float gg = tanh_(acc1[i][2]), og = sigm(acc1[i][3]);
                c1s[i] = fg * c1s[i] + ig * gg;
                float h1 = og * tanh_(c1s[i]);
                const int u = (w * 2 + i) * 4 + g;
                if (u < 62) wr1(smem, F_L1(q ^ 1, u >> 5), u, e, f2bf(h1));
            }
            // L2 acts (step t-1) -> h2 + partials
            if (t > 0) {
                float pr = 0.0f;
#pragma unroll
                for (int i = 0; i < 2; ++i) {
                    f32x4 a2 = acc2a[i] + acc2b[i];
                    float ig = sigm(a2[0]), fg = sigm(a2[1]);
                    float gg = tanh_(a2[2]), og = sigm(a2[3]);
                    c2s[i] = fg * c2s[i] + ig * gg;
                    float h2 = og * tanh_(c2s[i]);
                    const int u = (w * 2 + i) * 4 + g;
                    wr1(smem, F_H2(q ^ 1, u >> 5), u, e, f2bf(h2));
                    pr = fmaf(wlr[i], h2, pr);
                }
                pr += __shfl_xor(pr, 16);
                pr += __shfl_xor(pr, 32);
                if (l < 16) pparts[q * 128 + w * 16 + l] = pr;
            }
            xv = xnew;
        } else {
            // ======== B-order: h2 -> acc2b -> a1 -> acc2a/acc1 -> L2 acts -> L1 acts ====
#pragma unroll
            for (int s = 0; s < 2; ++s) h2f[s] = ld_fr(smem, F_H2(q, s), l);
            __builtin_amdgcn_s_setprio(1);
#pragma unroll
            for (int s = 0; s < 2; ++s)
#pragma unroll
                for (int i = 0; i < 2; ++i) {
                    acc2b[i] = __builtin_amdgcn_mfma_f32_16x16x32_bf16(w2h[i][s + 2], h2f[s], acc2b[i], 0, 0, 0);
                    acc2b[i] = __builtin_amdgcn_mfma_f32_16x16x32_bf16(w2l[i][s + 2], h2f[s], acc2b[i], 0, 0, 0);
                }
#pragma unroll
            for (int s = 0; s < 2; ++s) a1f[s] = ld_fr(smem, F_L1(q, s), l);
#pragma unroll
            for (int s = 0; s < 2; ++s)
#pragma unroll
                for (int i = 0; i < 2; ++i) {
                    acc2a[i] = __builtin_amdgcn_mfma_f32_16x16x32_bf16(w2h[i][s], a1f[s], acc2a[i], 0, 0, 0);
                    acc1[i]  = __builtin_amdgcn_mfma_f32_16x16x32_bf16(w1h[i][s], a1f[s], acc1[i],  0, 0, 0);
                    acc2a[i] = __builtin_amdgcn_mfma_f32_16x16x32_bf16(w2l[i][s], a1f[s], acc2a[i], 0, 0, 0);
                    acc1[i]  = __builtin_amdgcn_mfma_f32_16x16x32_bf16(w1l[i][s], a1f[s], acc1[i],  0, 0, 0);
                }
            __builtin_amdgcn_s_setprio(0);

            // L2 acts (step t-1) -> h2 + partials
            if (t > 0) {
                float pr = 0.0f;
#pragma unroll
                for (int i = 0; i < 2; ++i) {
                    f32x4 a2 = acc2a[i] + acc2b[i];
                    float ig = sigm(a2[0]), fg = sigm(a2[1]);
                    float gg = tanh_(a2[2]), og = sigm(a2[3]);
                    c2s[i] = fg * c2s[i] + ig * gg;
                    float h2 = og * tanh_(c2s[i]);
                    const int u = (w * 2 + i) * 4 + g;
                    wr1(smem, F_H2(q ^ 1, u >> 5), u, e, f2bf(h2));
                    pr = fmaf(wlr[i], h2, pr);
                }
                pr += __shfl_xor(pr, 16);
                pr += __shfl_xor(pr, 32);
                if (l < 16) pparts[q * 128 + w * 16 + l] = pr;
            }
            // L1 acts -> h1(t)
#pragma unroll
            for (int i = 0; i < 2; ++i) {
                float ig = sigm(acc1[i][0]), fg = sigm(acc1[i][1]);
                float gg = tanh_(acc1[i][2]), og = sigm(acc1[i][3]);
                c1s[i] = fg * c1s[i] + ig * gg;
                float h1 = og * tanh_(c1s[i]);
                const int u = (w * 2 + i) * 4 + g;
                if (u < 62) wr1(smem, F_L1(q ^ 1, u >> 5), u, e, f2bf(h1));
            }
        }

        __syncthreads();
    }

    // final output: out(LSEQ-1) from partials written at phase LSEQ
    if (w == 1 && l < 16) {
        const float* pp = pparts + (LSEQ & 1) * 128;
        float r = ((pp[l] + pp[16 + l]) + (pp[32 + l] + pp[48 + l])) +
                  ((pp[64 + l] + pp[80 + l]) + (pp[96 + l] + pp[112 + l]));
        out[(size_t)(b0 + l) * LSEQ + (LSEQ - 1)] = r + blv;
    }
}

extern "C" void kernel_launch(void* const* d_in, const int* in_sizes, int n_in,
                              void* d_out, int out_size, void* d_ws, size_t ws_size,
                              hipStream_t stream) {
    const float* x    = (const float*)d_in[0];
    const float* Wih1 = (const float*)d_in[1];
    const float* Whh1 = (const float*)d_in[2];
    const float* bih1 = (const float*)d_in[3];
    const float* bhh1 = (const float*)d_in[4];
    const float* Wih2 = (const float*)d_in[5];
    const float* Whh2 = (const float*)d_in[6];
    const float* bih2 = (const float*)d_in[7];
    const float* bhh2 = (const float*)d_in[8];
    const float* Wlin = (const float*)d_in[9];
    const float* blin = (const float*)d_in[10];
    float* ws  = (float*)d_ws;
    float* out = (float*)d_out;

    hipLaunchKernelGGL(prep_kernel, dim3(64), dim3(256), 0, stream,
                       Wih1, Whh1, bih1, bhh1, Wih2, Whh2, bih2, bhh2, Wlin, blin, ws);
    hipLaunchKernelGGL(lstm_kernel, dim3(NBLK), dim3(512), 0, stream, x, ws, out);
}

// Round 15
// 1014.933 us; speedup vs baseline: 2.0070x; 1.1408x over previous
//
#include <hip/hip_runtime.h>
#include <math.h>

#define H 51
#define LSEQ 999
#define BTOT 2048
#define E 16
#define NBLK (BTOT / E)     // 128 blocks x 1024 threads

#define ROWS 256            // 64 units * 4 gates (unit-major rows: row = u*4+m)
#define K1 64               // layer1 K: k=0..50 h1, k=62 const-1 (bias), k=63 x
#define K2 128              // layer2 K: k=0..50 h1, k=62 const-1 (bias), k=64..114 h2

// ws float offsets
#define WS_W1 0
#define WS_W2 (WS_W1 + ROWS * K1)
#define WS_WL (WS_W2 + ROWS * K2)
#define WS_BL (WS_WL + 64)

// LDS frames: 1 frame = one 32-K B-fragment plane (64 lanes x 16B); h is bf16 hi-only
#define FRAME 1024
#define NFRAMES 8
#define PART_OFF (NFRAMES * FRAME)
#define LDS_BYTES (PART_OFF + 2 * 256 * 4)   // double-buffered partials (16 waves x 16)

#define F_L1(b, s) ((b) * 2 + (s))        // [h1; 1; x] B-frags, double-buffered: 0..3
#define F_H2(b, s) (4 + (b) * 2 + (s))    // h2 B-frags, double-buffered: 4..7

typedef __attribute__((ext_vector_type(8))) short bf16x8;
typedef __attribute__((ext_vector_type(4))) float f32x4;

// ---------------- prep: padded cat-matrices, unit-major rows ----------------
// W1''[R][k]: k<51 = Whh1, k=62 = b1 (bias via const-1 slot), k=63 = Wih1
// W2''[R][k]: k<51 = Wih2 (h1 input), k=62 = b2, k=64..114 = Whh2
__global__ void prep_kernel(const float* __restrict__ Wih1, const float* __restrict__ Whh1,
                            const float* __restrict__ bih1, const float* __restrict__ bhh1,
                            const float* __restrict__ Wih2, const float* __restrict__ Whh2,
                            const float* __restrict__ bih2, const float* __restrict__ bhh2,
                            const float* __restrict__ Wlin, const float* __restrict__ blin,
                            float* __restrict__ ws) {
    int tid = threadIdx.x + blockIdx.x * blockDim.x;
    int nthr = blockDim.x * gridDim.x;
    for (int idx = tid; idx < ROWS * K1; idx += nthr) {
        int R = idx / K1, k = idx % K1;
        int u = R >> 2, m = R & 3;
        float v = 0.0f;
        if (u < H) {
            if (k < H) v = Whh1[(m * H + u) * H + k];
            else if (k == 62) v = bih1[m * H + u] + bhh1[m * H + u];
            else if (k == 63) v = Wih1[m * H + u];   // Wih1 is [204][1]
        }
        ws[WS_W1 + idx] = v;
    }
    for (int idx = tid; idx < ROWS * K2; idx += nthr) {
        int R = idx / K2, k = idx % K2;
        int u = R >> 2, m = R & 3;
        float v = 0.0f;
        if (u < H) {
            if (k < H) v = Wih2[(m * H + u) * H + k];
            else if (k == 62) v = bih2[m * H + u] + bhh2[m * H + u];
            else if (k >= 64 && k < 64 + H) v = Whh2[(m * H + u) * H + (k - 64)];
        }
        ws[WS_W2 + idx] = v;
    }
    for (int u = tid; u < 64; u += nthr) ws[WS_WL + u] = (u < H) ? Wlin[u] : 0.0f;
    if (tid == 0) ws[WS_BL] = blin[0];
}

// ---------------- helpers ----------------
__device__ __forceinline__ short f2bf(float f) {      // round-to-nearest-even
    unsigned u = __float_as_uint(f);
    unsigned r = (u + 0x7fffu + ((u >> 16) & 1u)) >> 16;
    return (short)r;
}
__device__ __forceinline__ float bf2f(short b) {
    return __uint_as_float(((unsigned)(unsigned short)b) << 16);
}
__device__ __forceinline__ float sigm(float x) {
    return __builtin_amdgcn_rcpf(1.0f + __expf(-x));
}
__device__ __forceinline__ float tanh_(float x) {
    return fmaf(-2.0f, __builtin_amdgcn_rcpf(__expf(2.0f * x) + 1.0f), 1.0f);
}
// scatter one bf16 h value into B-fragment layout: elems 0..3 <-> k=4g+j, 4..7 <-> 16+4g+j
__device__ __forceinline__ void wr1(char* base, int f, int k, int e, short hi) {
    const int kk = k & 31;
    const int gg = (kk & 15) >> 2;
    const int j  = (kk & 3) + ((kk >> 4) << 2);
    const int off = (gg * 16 + e) * 16 + j * 2;
    *(short*)(base + (size_t)f * FRAME + off) = hi;
}
__device__ __forceinline__ bf16x8 ld_fr(const char* base, int f, int l) {
    return *(const bf16x8*)(base + (size_t)f * FRAME + (size_t)l * 16);
}

// ---- main kernel: 16 waves x 1 row-tile (4 waves/SIMD TLP), E=16, h hi-only ----
__global__ void __launch_bounds__(1024)
lstm_kernel(const float* __restrict__ x, const float* __restrict__ ws,
            float* __restrict__ out) {
    __shared__ __align__(16) char smem[LDS_BYTES];

    const int tid = threadIdx.x;
    const int w = tid >> 6;        // 0..15; wave w owns row-tile T = w (units 4w..4w+3)
    const int l = tid & 63;
    const int g = l >> 4;
    const int e = l & 15;

    for (int i = tid; i < LDS_BYTES / 4; i += 1024) ((float*)smem)[i] = 0.0f;

    // ---- prologue: register-resident W fragments (hi/lo bf16 split; weights exact) ----
    bf16x8 w1h[2], w1l[2], w2h[4], w2l[4];
    const int rowA = w * 16 + e;
#pragma unroll
    for (int s = 0; s < 2; ++s) {
        bf16x8 hh, ll;
#pragma unroll
        for (int j = 0; j < 8; ++j) {
            const int k = s * 32 + ((j < 4) ? (4 * g + j) : (16 + 4 * g + (j - 4)));
            float wv = ws[WS_W1 + rowA * K1 + k];
            short hb = f2bf(wv);
            hh[j] = hb;
            ll[j] = f2bf(wv - bf2f(hb));
        }
        w1h[s] = hh; w1l[s] = ll;
    }
#pragma unroll
    for (int s = 0; s < 4; ++s) {
        bf16x8 hh, ll;
#pragma unroll
        for (int j = 0; j < 8; ++j) {
            const int k = s * 32 + ((j < 4) ? (4 * g + j) : (16 + 4 * g + (j - 4)));
            float wv = ws[WS_W2 + rowA * K2 + k];
            short hb = f2bf(wv);
            hh[j] = hb;
            ll[j] = f2bf(wv - bf2f(hb));
        }
        w2h[s] = hh; w2l[s] = ll;
    }
    const float wlr = ws[WS_WL + w * 4 + g];
    const float blv = ws[WS_BL];

    const int b0 = blockIdx.x * E;
    const float* xp = x + (size_t)(b0 + e) * LSEQ;   // used by wave0 lanes<16 only
    float* pparts = (float*)(smem + PART_OFF);

    __syncthreads();   // zero-init complete

    // const-1 (bf16 1.0) at k=62 of both a1 buffers (bias slot; u<62 guard protects it)
    if (tid < 32) {
        const int bb = tid >> 4, ee = tid & 15;
        // k=62 -> kk=30: gg=3, j=6 -> off=(48+ee)*16+12
        *(short*)(smem + (size_t)F_L1(bb, 1) * FRAME + (48 + ee) * 16 + 12) = (short)0x3F80;
    }
    float xv = 0.0f;
    if (w == 0 && l < 16) {
        float x0 = xp[0];
        wr1(smem, F_L1(0, 1), 63, e, f2bf(x0));   // x(0) -> buf0 k=63
        xv = xp[1];                                // x(1), written at phase 0
    }

    float c1s = 0.f, c2s = 0.f;

    __syncthreads();   // x(0) + const-1 visible

    // Phase t: L1 computes h1(t) from a1 = [h1(t-1); 1; x(t)] (buf q=t&1);
    //          L2 computes h2(t-1), out-partials(t-1) from same a1 + h2(t-2) (F_H2 buf q).
    for (int t = 0; t <= LSEQ; ++t) {
        const int q = t & 1;

        // ---- phase-start loads: 4 b128 per lane ----
        bf16x8 a1f[2], h2f[2];
#pragma unroll
        for (int s = 0; s < 2; ++s) {
            a1f[s] = ld_fr(smem, F_L1(q, s), l);
            h2f[s] = ld_fr(smem, F_H2(q, s), l);
        }

        // out(t-2): gather partials written at phase t-1 (buffer q^1)
        if (w == 1 && l < 16 && t >= 2) {
            const float* pp = pparts + (q ^ 1) * 256;
            float r = 0.0f;
#pragma unroll
            for (int ww = 0; ww < 16; ww += 4)
                r += ((pp[ww * 16 + l] + pp[(ww + 1) * 16 + l]) +
                      (pp[(ww + 2) * 16 + l] + pp[(ww + 3) * 16 + l]));
            out[(size_t)(b0 + l) * LSEQ + (t - 2)] = r + blv;
        }

        // write x(t+1) into next a1 buf; prefetch x(t+2)
        float xnew = 0.0f;
        if (w == 0 && l < 16) {
            xnew = xp[(t + 2 < LSEQ) ? (t + 2) : (LSEQ - 1)];
            wr1(smem, F_L1(q ^ 1, 1), 63, e, f2bf(xv));
        }

        // ---- MFMAs: 12 per wave, 3 independent 4-deep chains ----
        f32x4 acc1  = (f32x4){0.f, 0.f, 0.f, 0.f};
        f32x4 acc2a = (f32x4){0.f, 0.f, 0.f, 0.f};
        f32x4 acc2b = (f32x4){0.f, 0.f, 0.f, 0.f};
        __builtin_amdgcn_s_setprio(1);
#pragma unroll
        for (int s = 0; s < 2; ++s) {
            acc1  = __builtin_amdgcn_mfma_f32_16x16x32_bf16(w1h[s],     a1f[s], acc1,  0, 0, 0);
            acc2a = __builtin_amdgcn_mfma_f32_16x16x32_bf16(w2h[s],     a1f[s], acc2a, 0, 0, 0);
            acc2b = __builtin_amdgcn_mfma_f32_16x16x32_bf16(w2h[s + 2], h2f[s], acc2b, 0, 0, 0);
            acc1  = __builtin_amdgcn_mfma_f32_16x16x32_bf16(w1l[s],     a1f[s], acc1,  0, 0, 0);
            acc2a = __builtin_amdgcn_mfma_f32_16x16x32_bf16(w2l[s],     a1f[s], acc2a, 0, 0, 0);
            acc2b = __builtin_amdgcn_mfma_f32_16x16x32_bf16(w2l[s + 2], h2f[s], acc2b, 0, 0, 0);
        }
        __builtin_amdgcn_s_setprio(0);

        // ---- L1 activations -> h1(t) scatter into F_L1(q^1) (hi plane only) ----
        {
            float ig = sigm(acc1[0]), fg = sigm(acc1[1]);
            float gg = tanh_(acc1[2]), og = sigm(acc1[3]);
            c1s = fg * c1s + ig * gg;
            float h1 = og * tanh_(c1s);
            const int u = w * 4 + g;
            if (u < 62) wr1(smem, F_L1(q ^ 1, u >> 5), u, e, f2bf(h1));  // 62=const,63=x
        }

        // ---- L2 activations (step t-1) -> h2 scatter + output partial ----
        if (t > 0) {
            f32x4 a2 = acc2a + acc2b;
            float ig = sigm(a2[0]), fg = sigm(a2[1]);
            float gg = tanh_(a2[2]), og = sigm(a2[3]);
            c2s = fg * c2s + ig * gg;
            float h2 = og * tanh_(c2s);
            const int u = w * 4 + g;
            wr1(smem, F_H2(q ^ 1, u >> 5), u, e, f2bf(h2));
            float pr = wlr * h2;
            pr += __shfl_xor(pr, 16);
            pr += __shfl_xor(pr, 32);
            if (l < 16) pparts[q * 256 + w * 16 + l] = pr;
        }

        __syncthreads();
        xv = xnew;
    }

    // final output: out(LSEQ-1) from partials written at phase LSEQ
    if (w == 1 && l < 16) {
        const float* pp = pparts + (LSEQ & 1) * 256;
        float r = 0.0f;
#pragma unroll
        for (int ww = 0; ww < 16; ww += 4)
            r += ((pp[ww * 16 + l] + pp[(ww + 1) * 16 + l]) +
                  (pp[(ww + 2) * 16 + l] + pp[(ww + 3) * 16 + l]));
        out[(size_t)(b0 + l) * LSEQ + (LSEQ - 1)] = r + blv;
    }
}

extern "C" void kernel_launch(void* const* d_in, const int* in_sizes, int n_in,
                              void* d_out, int out_size, void* d_ws, size_t ws_size,
                              hipStream_t stream) {
    const float* x    = (const float*)d_in[0];
    const float* Wih1 = (const float*)d_in[1];
    const float* Whh1 = (const float*)d_in[2];
    const float* bih1 = (const float*)d_in[3];
    const float* bhh1 = (const float*)d_in[4];
    const float* Wih2 = (const float*)d_in[5];
    const float* Whh2 = (const float*)d_in[6];
    const float* bih2 = (const float*)d_in[7];
    const float* bhh2 = (const float*)d_in[8];
    const float* Wlin = (const float*)d_in[9];
    const float* blin = (const float*)d_in[10];
    float* ws  = (float*)d_ws;
    float* out = (float*)d_out;

    hipLaunchKernelGGL(prep_kernel, dim3(64), dim3(256), 0, stream,
                       Wih1, Whh1, bih1, bhh1, Wih2, Whh2, bih2, bhh2, Wlin, blin, ws);
    hipLaunchKernelGGL(lstm_kernel, dim3(NBLK), dim3(1024), 0, stream, x, ws, out);
}

// Round 16
// 977.866 us; speedup vs baseline: 2.0831x; 1.0379x over previous
//
#include <hip/hip_runtime.h>
#include <math.h>

#define H 51
#define LSEQ 999
#define BTOT 2048
#define E 16
#define NBLK (BTOT / E)     // 128 blocks

#define ROWS 256            // 64 units * 4 gates (unit-major rows: row = u*4+m)
#define K1 64               // layer1 K: k=0..50 h1, k=62 const-1 (bias), k=63 x
#define K2 128              // layer2 K: k=0..50 h1, k=62 const-1 (bias), k=64..114 h2

// ws float offsets
#define WS_W1 0
#define WS_W2 (WS_W1 + ROWS * K1)
#define WS_WL (WS_W2 + ROWS * K2)
#define WS_BL (WS_WL + 64)

// LDS frames: 1 frame = one 32-K B-fragment plane (64 lanes x 16B); h is bf16 hi-only
#define FRAME 1024
#define NFRAMES 8
#define PART_OFF (NFRAMES * FRAME)
#define LDS_BYTES (PART_OFF + 2 * 128 * 4)   // double-buffered partials (8 waves x 16)

#define F_L1(b, s) ((b) * 2 + (s))        // [h1; 1; x] B-frags, double-buffered: 0..3
#define F_H2(b, s) (4 + (b) * 2 + (s))    // h2 B-frags, double-buffered: 4..7

// exp2 pre-scaling: i/f/o rows scaled by L2E, g rows by 2*L2E (incl bias/x cols)
#define L2E  1.44269504088896f
#define L2E2 2.88539008177793f

#if defined(__has_builtin) && __has_builtin(__builtin_amdgcn_exp2f)
#define EXP2(x) __builtin_amdgcn_exp2f(x)
#else
#define EXP2(x) exp2f(x)
#endif

typedef __attribute__((ext_vector_type(8))) short bf16x8;
typedef __attribute__((ext_vector_type(4))) float f32x4;

// ---------------- prep: padded cat-matrices, unit-major rows, exp2-prescaled ----------------
// W1''[R][k]: k<51 = Whh1, k=62 = b1 (bias via const-1 slot), k=63 = Wih1; row scaled
// W2''[R][k]: k<51 = Wih2 (h1 input), k=62 = b2, k=64..114 = Whh2; row scaled
__global__ void prep_kernel(const float* __restrict__ Wih1, const float* __restrict__ Whh1,
                            const float* __restrict__ bih1, const float* __restrict__ bhh1,
                            const float* __restrict__ Wih2, const float* __restrict__ Whh2,
                            const float* __restrict__ bih2, const float* __restrict__ bhh2,
                            const float* __restrict__ Wlin, const float* __restrict__ blin,
                            float* __restrict__ ws) {
    int tid = threadIdx.x + blockIdx.x * blockDim.x;
    int nthr = blockDim.x * gridDim.x;
    for (int idx = tid; idx < ROWS * K1; idx += nthr) {
        int R = idx / K1, k = idx % K1;
        int u = R >> 2, m = R & 3;
        float v = 0.0f;
        if (u < H) {
            if (k < H) v = Whh1[(m * H + u) * H + k];
            else if (k == 62) v = bih1[m * H + u] + bhh1[m * H + u];
            else if (k == 63) v = Wih1[m * H + u];   // Wih1 is [204][1]
        }
        ws[WS_W1 + idx] = v * ((m == 2) ? L2E2 : L2E);
    }
    for (int idx = tid; idx < ROWS * K2; idx += nthr) {
        int R = idx / K2, k = idx % K2;
        int u = R >> 2, m = R & 3;
        float v = 0.0f;
        if (u < H) {
            if (k < H) v = Wih2[(m * H + u) * H + k];
            else if (k == 62) v = bih2[m * H + u] + bhh2[m * H + u];
            else if (k >= 64 && k < 64 + H) v = Whh2[(m * H + u) * H + (k - 64)];
        }
        ws[WS_W2 + idx] = v * ((m == 2) ? L2E2 : L2E);
    }
    for (int u = tid; u < 64; u += nthr) ws[WS_WL + u] = (u < H) ? Wlin[u] : 0.0f;
    if (tid == 0) ws[WS_BL] = blin[0];
}

// ---------------- helpers ----------------
__device__ __forceinline__ short f2bf(float f) {      // round-to-nearest-even
    unsigned u = __float_as_uint(f);
    unsigned r = (u + 0x7fffu + ((u >> 16) & 1u)) >> 16;
    return (short)r;
}
__device__ __forceinline__ float bf2f(short b) {
    return __uint_as_float(((unsigned)(unsigned short)b) << 16);
}
__device__ __forceinline__ float sigm2(float xp) {    // xp = x*log2e (pre-scaled)
    return __builtin_amdgcn_rcpf(1.0f + EXP2(-xp));   // neg folds into exp src mod
}
__device__ __forceinline__ float tanhp(float gp) {    // gp = 2g*log2e (pre-scaled)
    return fmaf(-2.0f, __builtin_amdgcn_rcpf(1.0f + EXP2(gp)), 1.0f);
}
__device__ __forceinline__ float tanhn(float c) {     // natural arg (c state)
    return fmaf(-2.0f, __builtin_amdgcn_rcpf(1.0f + EXP2(c * L2E2)), 1.0f);
}
// scatter one bf16 h value into B-fragment layout: elems 0..3 <-> k=4g+j, 4..7 <-> 16+4g+j
__device__ __forceinline__ void wr1(char* base, int f, int k, int e, short hi) {
    const int kk = k & 31;
    const int gg = (kk & 15) >> 2;
    const int j  = (kk & 3) + ((kk >> 4) << 2);
    const int off = (gg * 16 + e) * 16 + j * 2;
    *(short*)(base + (size_t)f * FRAME + off) = hi;
}
__device__ __forceinline__ bf16x8 ld_fr(const char* base, int f, int l) {
    return *(const bf16x8*)(base + (size_t)f * FRAME + (size_t)l * 16);
}

#define MFMA(a, b, c) __builtin_amdgcn_mfma_f32_16x16x32_bf16(a, b, c, 0, 0, 0)

// ------- main kernel: 8 waves x 2 row-tiles, E=16, h hi-only, 1-barrier skewed phase -------
__global__ void __launch_bounds__(512, 1)
lstm_kernel(const float* __restrict__ x, const float* __restrict__ ws,
            float* __restrict__ out) {
    __shared__ __align__(16) char smem[LDS_BYTES];

    const int tid = threadIdx.x;
    const int w = tid >> 6;        // 0..7; each wave owns 2 row-tiles T = w*2+i
    const int l = tid & 63;
    const int g = l >> 4;
    const int e = l & 15;

    for (int i = tid; i < LDS_BYTES / 4; i += 512) ((float*)smem)[i] = 0.0f;

    // ---- prologue: register-resident W fragments (hi/lo bf16 split; weights exact) ----
    bf16x8 w1h[2][2], w1l[2][2], w2h[2][4], w2l[2][4];
    float wlr[2];
#pragma unroll
    for (int i = 0; i < 2; ++i) {
        const int T = w * 2 + i;
        const int rowA = T * 16 + e;
#pragma unroll
        for (int s = 0; s < 2; ++s) {
            bf16x8 hh, ll;
#pragma unroll
            for (int j = 0; j < 8; ++j) {
                const int k = s * 32 + ((j < 4) ? (4 * g + j) : (16 + 4 * g + (j - 4)));
                float wv = ws[WS_W1 + rowA * K1 + k];
                short hb = f2bf(wv);
                hh[j] = hb;
                ll[j] = f2bf(wv - bf2f(hb));
            }
            w1h[i][s] = hh; w1l[i][s] = ll;
        }
#pragma unroll
        for (int s = 0; s < 4; ++s) {
            bf16x8 hh, ll;
#pragma unroll
            for (int j = 0; j < 8; ++j) {
                const int k = s * 32 + ((j < 4) ? (4 * g + j) : (16 + 4 * g + (j - 4)));
                float wv = ws[WS_W2 + rowA * K2 + k];
                short hb = f2bf(wv);
                hh[j] = hb;
                ll[j] = f2bf(wv - bf2f(hb));
            }
            w2h[i][s] = hh; w2l[i][s] = ll;
        }
        wlr[i] = ws[WS_WL + T * 4 + g];
    }
    const float blv = ws[WS_BL];

    const int b0 = blockIdx.x * E;
    const float* xp = x + (size_t)(b0 + e) * LSEQ;   // used by wave0 lanes<16 only
    float* pparts = (float*)(smem + PART_OFF);

    __syncthreads();   // zero-init complete

    // const-1 (bf16 1.0) at k=62 of both a1 buffers (bias slot; u<62 guard protects it)
    if (tid < 32) {
        const int bb = tid >> 4, ee = tid & 15;
        // k=62 -> kk=30: gg=3, j=6 -> off=(48+ee)*16+12
        *(short*)(smem + (size_t)F_L1(bb, 1) * FRAME + (48 + ee) * 16 + 12) = (short)0x3F80;
    }
    float xv = 0.0f;
    if (w == 0 && l < 16) {
        float x0 = xp[0];
        wr1(smem, F_L1(0, 1), 63, e, f2bf(x0));   // x(0) -> buf0 k=63
        xv = xp[1];                                // x(1), written at phase 0
    }

    float c1s[2] = {0.f, 0.f};
    float c2s[2] = {0.f, 0.f};
    const f32x4 fzero = {0.f, 0.f, 0.f, 0.f};     // persistent C-in for first MFMAs

    __syncthreads();   // x(0) + const-1 visible

    // Phase t: L1 computes h1(t) from a1 = [h1(t-1); 1; x(t)] (buf q=t&1);
    //          L2 computes h2(t-1), out-partials(t-1) from same a1 + h2(t-2) (F_H2 buf q).
    for (int t = 0; t <= LSEQ; ++t) {
        const int q = t & 1;

        // ---- phase-start loads: 4 b128 per lane ----
        bf16x8 a1f[2], h2f[2];
#pragma unroll
        for (int s = 0; s < 2; ++s) {
            a1f[s] = ld_fr(smem, F_L1(q, s), l);
            h2f[s] = ld_fr(smem, F_H2(q, s), l);
        }

        // out(t-2): gather partials written at phase t-1 (buffer q^1)
        if (w == 1 && l < 16 && t >= 2) {
            const float* pp = pparts + (q ^ 1) * 128;
            float r = ((pp[l] + pp[16 + l]) + (pp[32 + l] + pp[48 + l])) +
                      ((pp[64 + l] + pp[80 + l]) + (pp[96 + l] + pp[112 + l]));
            out[(size_t)(b0 + l) * LSEQ + (t - 2)] = r + blv;
        }

        // write x(t+1) into next a1 buf; prefetch x(t+2)
        float xnew = 0.0f;
        if (w == 0 && l < 16) {
            xnew = xp[(t + 2 < LSEQ) ? (t + 2) : (LSEQ - 1)];
            wr1(smem, F_L1(q ^ 1, 1), 63, e, f2bf(xv));
        }

        // ---- MFMAs: 24 per wave, 6 independent 4-deep chains; fzero C-in (no movs) ----
        f32x4 acc1[2], acc2a[2], acc2b[2];
        __builtin_amdgcn_s_setprio(1);
#pragma unroll
        for (int i = 0; i < 2; ++i) {
            acc1[i]  = MFMA(w1h[i][0], a1f[0], fzero);
            acc2a[i] = MFMA(w2h[i][0], a1f[0], fzero);
            acc2b[i] = MFMA(w2h[i][2], h2f[0], fzero);
            acc1[i]  = MFMA(w1l[i][0], a1f[0], acc1[i]);
            acc2a[i] = MFMA(w2l[i][0], a1f[0], acc2a[i]);
            acc2b[i] = MFMA(w2l[i][2], h2f[0], acc2b[i]);
            acc1[i]  = MFMA(w1h[i][1], a1f[1], acc1[i]);
            acc2a[i] = MFMA(w2h[i][1], a1f[1], acc2a[i]);
            acc2b[i] = MFMA(w2h[i][3], h2f[1], acc2b[i]);
            acc1[i]  = MFMA(w1l[i][1], a1f[1], acc1[i]);
            acc2a[i] = MFMA(w2l[i][1], a1f[1], acc2a[i]);
            acc2b[i] = MFMA(w2l[i][3], h2f[1], acc2b[i]);
        }
        __builtin_amdgcn_s_setprio(0);

        // ---- L1 activations (pre-scaled gates) -> h1(t) scatter into F_L1(q^1) ----
#pragma unroll
        for (int i = 0; i < 2; ++i) {
            float ig = sigm2(acc1[i][0]), fg = sigm2(acc1[i][1]);
            float gg = tanhp(acc1[i][2]), og = sigm2(acc1[i][3]);
            c1s[i] = fg * c1s[i] + ig * gg;
            float h1 = og * tanhn(c1s[i]);
            const int u = (w * 2 + i) * 4 + g;
            if (u < 62) wr1(smem, F_L1(q ^ 1, u >> 5), u, e, f2bf(h1));  // 62=const,63=x
        }

        // ---- L2 activations (step t-1) -> h2 scatter + output partial ----
        if (t > 0) {
            float pr = 0.0f;
#pragma unroll
            for (int i = 0; i < 2; ++i) {
                f32x4 a2 = acc2a[i] + acc2b[i];
                float ig = sigm2(a2[0]), fg = sigm2(a2[1]);
                float gg = tanhp(a2[2]), og = sigm2(a2[3]);
                c2s[i] = fg * c2s[i] + ig * gg;
                float h2 = og * tanhn(c2s[i]);
                const int u = (w * 2 + i) * 4 + g;
                wr1(smem, F_H2(q ^ 1, u >> 5), u, e, f2bf(h2));
                pr = fmaf(wlr[i], h2, pr);
            }
            pr += __shfl_xor(pr, 16);
            pr += __shfl_xor(pr, 32);
            if (l < 16) pparts[q * 128 + w * 16 + l] = pr;
        }

        __syncthreads();
        xv = xnew;
    }

    // final output: out(LSEQ-1) from partials written at phase LSEQ
    if (w == 1 && l < 16) {
        const float* pp = pparts + (LSEQ & 1) * 128;
        float r = ((pp[l] + pp[16 + l]) + (pp[32 + l] + pp[48 + l])) +
                  ((pp[64 + l] + pp[80 + l]) + (pp[96 + l] + pp[112 + l]));
        out[(size_t)(b0 + l) * LSEQ + (LSEQ - 1)] = r + blv;
    }
}

extern "C" void kernel_launch(void* const* d_in, const int* in_sizes, int n_in,
                              void* d_out, int out_size, void* d_ws, size_t ws_size,
                              hipStream_t stream) {
    const float* x    = (const float*)d_in[0];
    const float* Wih1 = (const float*)d_in[1];
    const float* Whh1 = (const float*)d_in[2];
    const float* bih1 = (const float*)d_in[3];
    const float* bhh1 = (const float*)d_in[4];
    const float* Wih2 = (const float*)d_in[5];
    const float* Whh2 = (const float*)d_in[6];
    const float* bih2 = (const float*)d_in[7];
    const float* bhh2 = (const float*)d_in[8];
    const float* Wlin = (const float*)d_in[9];
    const float* blin = (const float*)d_in[10];
    float* ws  = (float*)d_ws;
    float* out = (float*)d_out;

    hipLaunchKernelGGL(prep_kernel, dim3(64), dim3(256), 0, stream,
                       Wih1, Whh1, bih1, bhh1, Wih2, Whh2, bih2, bhh2, Wlin, blin, ws);
    hipLaunchKernelGGL(lstm_kernel, dim3(NBLK), dim3(512), 0, stream, x, ws, out);
}